// Round 1
// baseline (384.064 us; speedup 1.0000x reference)
//
#include <hip/hip_runtime.h>
#include <stdint.h>

typedef __attribute__((ext_vector_type(4))) float f32x4;
typedef __attribute__((ext_vector_type(8))) short s16x8;
typedef __attribute__((ext_vector_type(4))) short s16x4;
typedef __attribute__((ext_vector_type(4))) int   i32x4;

// Problem constants: B=2, N=2048, DIM=1024, H=16, DH=64, DI=1024, M = B*N = 4096

__device__ __forceinline__ short f2bf(float f) {
  union { float f; unsigned u; } v; v.f = f;
  unsigned r = (v.u + 0x7fff + ((v.u >> 16) & 1)) >> 16;  // RNE
  return (short)r;
}

// ---------------- fp32 -> bf16 convert (vectorized) ----------------
__global__ __launch_bounds__(256) void cvt_f32_bf16(const float* __restrict__ in,
                                                    short* __restrict__ out, int n4) {
  int i = blockIdx.x * 256 + threadIdx.x;
  if (i >= n4) return;
  float4 f = ((const float4*)in)[i];
  s16x4 o; o.x = f2bf(f.x); o.y = f2bf(f.y); o.z = f2bf(f.z); o.w = f2bf(f.w);
  ((s16x4*)out)[i] = o;
}

// ---------------- transpose+convert: in[K][N] f32 -> out[N][K] bf16 ----------------
__global__ void transpose_cvt(const float* __restrict__ in, short* __restrict__ out,
                              int K, int N) {
  __shared__ float t[32][33];
  int nt = blockIdx.x * 32, kt = blockIdx.y * 32;
  int tx = threadIdx.x, ty = threadIdx.y;  // 32 x 8
  #pragma unroll
  for (int i = 0; i < 4; i++) t[ty + 8*i][tx] = in[(size_t)(kt + ty + 8*i) * N + nt + tx];
  __syncthreads();
  #pragma unroll
  for (int i = 0; i < 4; i++)
    out[(size_t)(nt + ty + 8*i) * K + kt + tx] = f2bf(t[tx][ty + 8*i]);
}

// ---------------- transpose V region of QKV into VT[bh*64+d][n] ----------------
__global__ void transpose_v(const short* __restrict__ qkv, short* __restrict__ vt) {
  int bh = blockIdx.y; int b = bh >> 4, h = bh & 15;
  int nt = blockIdx.x * 32;
  int tx = threadIdx.x, ty = threadIdx.y;  // 32 x 8
  __shared__ short t[32][33];
  #pragma unroll
  for (int dt = 0; dt < 2; dt++) {
    #pragma unroll
    for (int i = 0; i < 4; i++)
      t[ty + 8*i][tx] = qkv[(size_t)(b*2048 + nt + ty + 8*i) * 3072 + 2048 + h*64 + dt*32 + tx];
    __syncthreads();
    #pragma unroll
    for (int i = 0; i < 4; i++)
      vt[(size_t)(bh*64 + dt*32 + ty + 8*i) * 2048 + nt + tx] = t[tx][ty + 8*i];
    __syncthreads();
  }
}

// ---------------- 128x128 tile MFMA GEMM: C[M][N] = A[M][K] * Bt[N][K]^T ----------------
template<int CF32>
__global__ __launch_bounds__(256) void gemm_bt(const short* __restrict__ A,
                                               const short* __restrict__ Bt,
                                               void* __restrict__ C,
                                               int M, int N, int K) {
  __shared__ short As[128][32];
  __shared__ short Bs[128][32];
  const int tid = threadIdx.x;
  const int wave = tid >> 6, lane = tid & 63;
  const int l15 = lane & 15, l4 = lane >> 4;
  const int bm = blockIdx.y * 128, bn = blockIdx.x * 128;
  const int wr = (wave >> 1) * 64, wc = (wave & 1) * 64;
  const int r = tid >> 2, c8 = (tid & 3) * 8;
  f32x4 acc[4][4] = {};
  for (int k0 = 0; k0 < K; k0 += 32) {
    i32x4 a0 = *(const i32x4*)&A [(size_t)(bm + r)      * K + k0 + c8];
    i32x4 a1 = *(const i32x4*)&A [(size_t)(bm + r + 64) * K + k0 + c8];
    i32x4 b0 = *(const i32x4*)&Bt[(size_t)(bn + r)      * K + k0 + c8];
    i32x4 b1 = *(const i32x4*)&Bt[(size_t)(bn + r + 64) * K + k0 + c8];
    __syncthreads();
    *(i32x4*)&As[r][c8]      = a0;
    *(i32x4*)&As[r + 64][c8] = a1;
    *(i32x4*)&Bs[r][c8]      = b0;
    *(i32x4*)&Bs[r + 64][c8] = b1;
    __syncthreads();
    s16x8 af[4], bf[4];
    #pragma unroll
    for (int m = 0; m < 4; m++) af[m] = *(const s16x8*)&As[wr + m*16 + l15][l4*8];
    #pragma unroll
    for (int n = 0; n < 4; n++) bf[n] = *(const s16x8*)&Bs[wc + n*16 + l15][l4*8];
    #pragma unroll
    for (int m = 0; m < 4; m++)
      #pragma unroll
      for (int n = 0; n < 4; n++)
        acc[m][n] = __builtin_amdgcn_mfma_f32_16x16x32_bf16(af[m], bf[n], acc[m][n], 0, 0, 0);
  }
  #pragma unroll
  for (int m = 0; m < 4; m++)
    #pragma unroll
    for (int n = 0; n < 4; n++)
      #pragma unroll
      for (int j = 0; j < 4; j++) {
        int row = bm + wr + m*16 + l4*4 + j;
        int col = bn + wc + n*16 + l15;
        float v = acc[m][n][j];
        if (CF32) ((float*)C)[(size_t)row * N + col] = v;
        else      ((short*)C)[(size_t)row * N + col] = f2bf(v);
      }
}

// ---------------- fused masked flash attention ----------------
// QKV[4096][3072] bf16 (Q | K | V per head), VT[(bh*64+d)][2048] bf16,
// mask[b][2048] int, O[4096][1024] bf16.
__global__ __launch_bounds__(256) void attn_kernel(const short* __restrict__ QKV,
                                                   const short* __restrict__ VT,
                                                   const int* __restrict__ mask,
                                                   short* __restrict__ O) {
  __shared__ float biasLds[2048];
  __shared__ short Pl[4][16][32];
  const int qt = blockIdx.x;   // 0..31 (q tile of 64 rows)
  const int bh = blockIdx.y;   // 0..31
  const int b = bh >> 4, h = bh & 15;
  const int tid = threadIdx.x;
  const int wave = tid >> 6, lane = tid & 63;
  const int l15 = lane & 15, l4 = lane >> 4;

  for (int j = tid; j < 2048; j += 256)
    biasLds[j] = mask[b*2048 + j] ? 0.0f : -1e30f;
  __syncthreads();

  const int q0 = qt * 64 + wave * 16;
  // Q as B-fragments (lane: q = l15, d = s*32 + l4*8 + j)
  s16x8 qb[2];
  #pragma unroll
  for (int s = 0; s < 2; s++)
    qb[s] = *(const s16x8*)&QKV[(size_t)(b*2048 + q0 + l15) * 3072 + h*64 + s*32 + l4*8];

  f32x4 oacc[4] = {};
  float mrun = -3.0e38f, lsum = 0.0f;
  const f32x4 zf = {0.f, 0.f, 0.f, 0.f};

  const short* Kbase = QKV + (size_t)(b*2048) * 3072 + 1024 + h*64;
  const short* Vbase = VT + (size_t)(bh*64) * 2048;

  for (int kt = 0; kt < 64; kt++) {
    // S^T = K * Q^T  (two 16-key halves, two d-steps each)
    f32x4 st[2];
    #pragma unroll
    for (int h2 = 0; h2 < 2; h2++) {
      s16x8 ka0 = *(const s16x8*)&Kbase[(size_t)(kt*32 + h2*16 + l15) * 3072 + 0  + l4*8];
      s16x8 ka1 = *(const s16x8*)&Kbase[(size_t)(kt*32 + h2*16 + l15) * 3072 + 32 + l4*8];
      f32x4 s = __builtin_amdgcn_mfma_f32_16x16x32_bf16(ka0, qb[0], zf, 0, 0, 0);
      s       = __builtin_amdgcn_mfma_f32_16x16x32_bf16(ka1, qb[1], s,  0, 0, 0);
      st[h2] = s;
    }
    // scale + mask bias; lane holds 8 keys for its q (= l15)
    float vals[8];
    #pragma unroll
    for (int h2 = 0; h2 < 2; h2++)
      #pragma unroll
      for (int rr = 0; rr < 4; rr++) {
        int key = kt*32 + h2*16 + l4*4 + rr;
        vals[h2*4 + rr] = st[h2][rr] * 0.125f + biasLds[key];
      }
    // online softmax (row state duplicated across the 4 lane-groups, kept in sync)
    float tm = vals[0];
    #pragma unroll
    for (int i = 1; i < 8; i++) tm = fmaxf(tm, vals[i]);
    tm = fmaxf(tm, __shfl_xor(tm, 16));
    tm = fmaxf(tm, __shfl_xor(tm, 32));
    float mnew = fmaxf(mrun, tm);
    float corr = __expf(mrun - mnew);
    float p[8], psum = 0.f;
    #pragma unroll
    for (int i = 0; i < 8; i++) { p[i] = __expf(vals[i] - mnew); psum += p[i]; }
    psum += __shfl_xor(psum, 16);
    psum += __shfl_xor(psum, 32);
    lsum = lsum * corr + psum;
    mrun = mnew;
    // re-layout P via per-wave LDS: Pl[q][key]
    #pragma unroll
    for (int h2 = 0; h2 < 2; h2++)
      #pragma unroll
      for (int rr = 0; rr < 4; rr++)
        Pl[wave][l15][h2*16 + l4*4 + rr] = f2bf(p[h2*4 + rr]);
    s16x8 pb = *(const s16x8*)&Pl[wave][l15][l4*8];  // B-frag: q=l15, key=l4*8+j
    // O^T += V^T * P^T  (4 d-fragments of 16)
    #pragma unroll
    for (int f = 0; f < 4; f++) {
      s16x8 vf = *(const s16x8*)&Vbase[(size_t)(f*16 + l15) * 2048 + kt*32 + l4*8];
      #pragma unroll
      for (int rr = 0; rr < 4; rr++) oacc[f][rr] *= corr;
      oacc[f] = __builtin_amdgcn_mfma_f32_16x16x32_bf16(vf, pb, oacc[f], 0, 0, 0);
    }
  }
  float inv = 1.0f / lsum;
  #pragma unroll
  for (int f = 0; f < 4; f++) {
    s16x4 o;
    o.x = f2bf(oacc[f][0] * inv); o.y = f2bf(oacc[f][1] * inv);
    o.z = f2bf(oacc[f][2] * inv); o.w = f2bf(oacc[f][3] * inv);
    *(s16x4*)&O[(size_t)(b*2048 + q0 + l15) * 1024 + h*64 + f*16 + l4*4] = o;
  }
}

extern "C" void kernel_launch(void* const* d_in, const int* in_sizes, int n_in,
                              void* d_out, int out_size, void* d_ws, size_t ws_size,
                              hipStream_t stream) {
  const float* x    = (const float*)d_in[0];
  const int*   mask = (const int*)  d_in[1];
  const float* Wq   = (const float*)d_in[2];
  const float* Wkv  = (const float*)d_in[3];
  const float* Wo   = (const float*)d_in[4];
  float* out = (float*)d_out;

  char* ws = (char*)d_ws;
  short* xb  = (short*)(ws);                 //  8 MB  [4096][1024]
  short* W1T = (short*)(ws + 8388608);       //  6 MB  [3072][1024]
  short* WoT = (short*)(ws + 14680064);      //  2 MB  [1024][1024]
  short* QKV = (short*)(ws + 16777216);      // 24 MB  [4096][3072]
  short* VT  = (short*)(ws + 41943040);      //  8 MB  [32*64][2048]
  short* O   = (short*)(ws + 50331648);      //  8 MB  [4096][1024]

  cvt_f32_bf16<<<4096, 256, 0, stream>>>(x, xb, 4194304 / 4);
  transpose_cvt<<<dim3(32, 32), dim3(32, 8), 0, stream>>>(Wq,  W1T,               1024, 1024);
  transpose_cvt<<<dim3(64, 32), dim3(32, 8), 0, stream>>>(Wkv, W1T + 1024*1024,   1024, 2048);
  transpose_cvt<<<dim3(32, 32), dim3(32, 8), 0, stream>>>(Wo,  WoT,               1024, 1024);
  gemm_bt<0><<<dim3(24, 32), 256, 0, stream>>>(xb, W1T, QKV, 4096, 3072, 1024);
  transpose_v<<<dim3(64, 32), dim3(32, 8), 0, stream>>>(QKV, VT);
  attn_kernel<<<dim3(32, 32), 256, 0, stream>>>(QKV, VT, mask, O);
  gemm_bt<1><<<dim3(8, 32), 256, 0, stream>>>(O, WoT, out, 4096, 1024, 1024);
}

// Round 4
// 268.420 us; speedup vs baseline: 1.4308x; 1.4308x over previous
//
#include <hip/hip_runtime.h>
#include <stdint.h>

typedef __attribute__((ext_vector_type(4))) float f32x4;
typedef __attribute__((ext_vector_type(8))) short s16x8;
typedef __attribute__((ext_vector_type(4))) short s16x4;
typedef __attribute__((ext_vector_type(4))) int   i32x4;

// Problem constants: B=2, N=2048, DIM=1024, H=16, DH=64, DI=1024, M = B*N = 4096

__device__ __forceinline__ short f2bf(float f) {
  union { float f; unsigned u; } v; v.f = f;
  unsigned r = (v.u + 0x7fff + ((v.u >> 16) & 1)) >> 16;  // RNE
  return (short)r;
}

__device__ __forceinline__ void gload16(const void* g, void* l) {
  __builtin_amdgcn_global_load_lds(
      (const __attribute__((address_space(1))) unsigned int*)g,
      (__attribute__((address_space(3))) unsigned int*)l, 16, 0, 0);
}

// ---------------- fp32 -> bf16 convert (vectorized) ----------------
__global__ __launch_bounds__(256) void cvt_f32_bf16(const float* __restrict__ in,
                                                    short* __restrict__ out, int n4) {
  int i = blockIdx.x * 256 + threadIdx.x;
  if (i >= n4) return;
  float4 f = ((const float4*)in)[i];
  s16x4 o; o.x = f2bf(f.x); o.y = f2bf(f.y); o.z = f2bf(f.z); o.w = f2bf(f.w);
  ((s16x4*)out)[i] = o;
}

// ---------------- transpose+convert: in[K][N] f32 -> out[N][K] bf16 ----------------
__global__ void transpose_cvt(const float* __restrict__ in, short* __restrict__ out,
                              int K, int N) {
  __shared__ float t[32][33];
  int nt = blockIdx.x * 32, kt = blockIdx.y * 32;
  int tx = threadIdx.x, ty = threadIdx.y;  // 32 x 8
  #pragma unroll
  for (int i = 0; i < 4; i++) t[ty + 8*i][tx] = in[(size_t)(kt + ty + 8*i) * N + nt + tx];
  __syncthreads();
  #pragma unroll
  for (int i = 0; i < 4; i++)
    out[(size_t)(nt + ty + 8*i) * K + kt + tx] = f2bf(t[tx][ty + 8*i]);
}

// ---------------- transpose V region of QKV into VT[bh*64+d][n] ----------------
__global__ void transpose_v(const short* __restrict__ qkv, short* __restrict__ vt) {
  int bh = blockIdx.y; int b = bh >> 4, h = bh & 15;
  int nt = blockIdx.x * 32;
  int tx = threadIdx.x, ty = threadIdx.y;  // 32 x 8
  __shared__ short t[32][33];
  #pragma unroll
  for (int dt = 0; dt < 2; dt++) {
    #pragma unroll
    for (int i = 0; i < 4; i++)
      t[ty + 8*i][tx] = qkv[(size_t)(b*2048 + nt + ty + 8*i) * 3072 + 2048 + h*64 + dt*32 + tx];
    __syncthreads();
    #pragma unroll
    for (int i = 0; i < 4; i++)
      vt[(size_t)(bh*64 + dt*32 + ty + 8*i) * 2048 + nt + tx] = t[tx][ty + 8*i];
    __syncthreads();
  }
}

// ---------------- 128x128 tile MFMA GEMM (m97 structure): C = A * Bt^T ----------------
template<int CF32>
__global__ __launch_bounds__(256) void gemm_bt(const short* __restrict__ A,
                                               const short* __restrict__ Bt,
                                               void* __restrict__ C,
                                               int M, int N, int K) {
  __shared__ short As[128][32];
  __shared__ short Bs[128][32];
  const int tid = threadIdx.x;
  const int wave = tid >> 6, lane = tid & 63;
  const int l15 = lane & 15, l4 = lane >> 4;
  const int bm = blockIdx.y * 128, bn = blockIdx.x * 128;
  const int wr = (wave >> 1) * 64, wc = (wave & 1) * 64;
  const int r = tid >> 2, c8 = (tid & 3) * 8;
  const short* aS0 = &A [(size_t)(bm + r)      * K + c8];
  const short* aS1 = &A [(size_t)(bm + 64 + r) * K + c8];
  const short* bS0 = &Bt[(size_t)(bn + r)      * K + c8];
  const short* bS1 = &Bt[(size_t)(bn + 64 + r) * K + c8];
  char* aD0 = (char*)As + tid*16; char* aD1 = (char*)As + 4096 + tid*16;
  char* bD0 = (char*)Bs + tid*16; char* bD1 = (char*)Bs + 4096 + tid*16;
  f32x4 acc[4][4] = {};
  for (int k0 = 0; k0 < K; k0 += 32) {
    gload16(aS0 + k0, aD0);
    gload16(aS1 + k0, aD1);
    gload16(bS0 + k0, bD0);
    gload16(bS1 + k0, bD1);
    __syncthreads();   // drains vmcnt(0) + barrier: tile visible to all waves
    s16x8 af[4], bf[4];
    #pragma unroll
    for (int m = 0; m < 4; m++) af[m] = *(const s16x8*)&As[wr + m*16 + l15][l4*8];
    #pragma unroll
    for (int n = 0; n < 4; n++) bf[n] = *(const s16x8*)&Bs[wc + n*16 + l15][l4*8];
    #pragma unroll
    for (int m = 0; m < 4; m++)
      #pragma unroll
      for (int n = 0; n < 4; n++)
        acc[m][n] = __builtin_amdgcn_mfma_f32_16x16x32_bf16(af[m], bf[n], acc[m][n], 0, 0, 0);
    __syncthreads();   // all waves done reading before next overwrite
  }
  #pragma unroll
  for (int m = 0; m < 4; m++)
    #pragma unroll
    for (int n = 0; n < 4; n++)
      #pragma unroll
      for (int j = 0; j < 4; j++) {
        int row = bm + wr + m*16 + l4*4 + j;
        int col = bn + wc + n*16 + l15;
        float v = acc[m][n][j];
        if (CF32) ((float*)C)[(size_t)row * N + col] = v;
        else      ((short*)C)[(size_t)row * N + col] = f2bf(v);
      }
}

// ---------------- fused masked flash attention ----------------
// KVBLK=64, K/V double-buffered in LDS (XOR-swizzled), ONE __syncthreads per
// K-tile: stage(t+1) issued before compute(t), barrier at iteration end drains
// it. 4 waves x 16 q-rows. QKV[4096][3072], VT[bh*64+d][2048], mask int,
// O[4096][1024] bf16.
__global__ __launch_bounds__(256) void attn_kernel(const short* __restrict__ QKV,
                                                   const short* __restrict__ VT,
                                                   const int* __restrict__ mask,
                                                   short* __restrict__ O) {
  __shared__ float biasLds[2048];
  __shared__ short Ks[2][64*64];    // swizzled [key][d]
  __shared__ short Vs[2][64*64];    // swizzled [d][key]
  __shared__ short Pl[4][16*64];    // per-wave swizzled [q][key]

  const int qt = blockIdx.x;   // 0..31
  const int bh = blockIdx.y;   // 0..31
  const int b = bh >> 4, h = bh & 15;
  const int tid = threadIdx.x;
  const int wave = tid >> 6, lane = tid & 63;
  const int l15 = lane & 15, l4 = lane >> 4;

  // Q fragments (global loads; drained by the prologue __syncthreads)
  const int q0 = qt * 64 + wave * 16;
  s16x8 qb0 = *(const s16x8*)&QKV[(size_t)(b*2048 + q0 + l15) * 3072 + h*64 + l4*8];
  s16x8 qb1 = *(const s16x8*)&QKV[(size_t)(b*2048 + q0 + l15) * 3072 + h*64 + 32 + l4*8];

  for (int j = tid; j < 2048; j += 256)
    biasLds[j] = mask[b*2048 + j] ? 0.0f : -1e38f;

  // staging: thread -> (row r0, 16B chunk c0); source pre-swizzled so the LDS
  // image is LDS[r][c] = G[r][c ^ (r&7)] with a linear global_load_lds dest.
  const int r0 = tid >> 3, c0 = tid & 7;
  const int cs = (c0 ^ (r0 & 7)) * 8;   // shorts
  const short* Kg = QKV + (size_t)(b*2048)*3072 + 1024 + h*64;
  const short* Vg = VT + (size_t)(bh*64)*2048;
  const short* kS0 = Kg + (size_t)r0*3072 + cs;
  const short* kS1 = Kg + (size_t)(r0+32)*3072 + cs;
  const short* vS0 = Vg + (size_t)r0*2048 + cs;
  const short* vS1 = Vg + (size_t)(r0+32)*2048 + cs;

  // prologue: stage tile 0 into buffer 0
  gload16(kS0, (char*)Ks[0] + tid*16);
  gload16(kS1, (char*)Ks[0] + 4096 + tid*16);
  gload16(vS0, (char*)Vs[0] + tid*16);
  gload16(vS1, (char*)Vs[0] + 4096 + tid*16);
  __syncthreads();   // bias + tile 0 ready

  f32x4 oacc[4] = {};
  float mrun = -3.0e38f, lsum = 0.0f;
  const f32x4 zf = {0.f, 0.f, 0.f, 0.f};
  const int swz = (l15 & 7) << 4;
  char* PlB = (char*)&Pl[wave][0];
  const int rowB = l15 * 128;

  for (int kt = 0; kt < 32; kt++) {
    const int cur = kt & 1;
    // issue prefetch of tile kt+1 into the other buffer (overlaps compute)
    if (kt + 1 < 32) {
      gload16(kS0 + (size_t)(kt+1)*196608, (char*)Ks[cur^1] + tid*16);
      gload16(kS1 + (size_t)(kt+1)*196608, (char*)Ks[cur^1] + 4096 + tid*16);
      gload16(vS0 + (kt+1)*64,             (char*)Vs[cur^1] + tid*16);
      gload16(vS1 + (kt+1)*64,             (char*)Vs[cur^1] + 4096 + tid*16);
    }
    const char* KsB = (const char*)Ks[cur];
    const char* VsB = (const char*)Vs[cur];

    // ---- QK^T (swapped: rows=keys, cols=q) + softmax ----
    float vals[16];
    #pragma unroll
    for (int g = 0; g < 4; g++) {
      s16x8 ka0 = *(const s16x8*)(KsB + (g*16 + l15)*128 + ((l4*16) ^ swz));
      s16x8 ka1 = *(const s16x8*)(KsB + (g*16 + l15)*128 + ((64 + l4*16) ^ swz));
      f32x4 s = __builtin_amdgcn_mfma_f32_16x16x32_bf16(ka0, qb0, zf, 0, 0, 0);
      s       = __builtin_amdgcn_mfma_f32_16x16x32_bf16(ka1, qb1, s,  0, 0, 0);
      const float* bp = &biasLds[kt*64 + g*16 + l4*4];
      #pragma unroll
      for (int rr = 0; rr < 4; rr++)
        vals[g*4 + rr] = s[rr] * 0.18033688011112042f + bp[rr];  // 0.125*log2(e)
    }
    float tm = vals[0];
    #pragma unroll
    for (int i = 1; i < 16; i++) tm = fmaxf(tm, vals[i]);
    tm = fmaxf(tm, __shfl_xor(tm, 16));
    tm = fmaxf(tm, __shfl_xor(tm, 32));
    float mnew = fmaxf(mrun, tm);
    float corr = exp2f(mrun - mnew);
    float psum = 0.f;
    #pragma unroll
    for (int i = 0; i < 16; i++) { vals[i] = exp2f(vals[i] - mnew); psum += vals[i]; }
    psum += __shfl_xor(psum, 16);
    psum += __shfl_xor(psum, 32);
    lsum = lsum * corr + psum;
    mrun = mnew;
    #pragma unroll
    for (int g = 0; g < 4; g++) {
      s16x4 pk;
      pk.x = f2bf(vals[g*4+0]); pk.y = f2bf(vals[g*4+1]);
      pk.z = f2bf(vals[g*4+2]); pk.w = f2bf(vals[g*4+3]);
      *(s16x4*)(PlB + rowB + ((g*32 + l4*8) ^ swz)) = pk;  // same-wave round trip
    }

    // ---- PV: O^T += V^T * P^T ----
    #pragma unroll
    for (int f = 0; f < 4; f++)
      #pragma unroll
      for (int j = 0; j < 4; j++) oacc[f][j] *= corr;
    #pragma unroll
    for (int kh = 0; kh < 2; kh++) {
      s16x8 pb = *(const s16x8*)(PlB + rowB + ((kh*64 + l4*16) ^ swz));
      #pragma unroll
      for (int f = 0; f < 4; f++) {
        s16x8 vf = *(const s16x8*)(VsB + (f*16 + l15)*128 + ((kh*64 + l4*16) ^ swz));
        oacc[f] = __builtin_amdgcn_mfma_f32_16x16x32_bf16(vf, pb, oacc[f], 0, 0, 0);
      }
    }
    __syncthreads();  // all waves done with buf[cur]; prefetch of buf[cur^1] drained
  }

  float inv = 1.0f / lsum;
  #pragma unroll
  for (int f = 0; f < 4; f++) {
    s16x4 o;
    o.x = f2bf(oacc[f][0] * inv); o.y = f2bf(oacc[f][1] * inv);
    o.z = f2bf(oacc[f][2] * inv); o.w = f2bf(oacc[f][3] * inv);
    *(s16x4*)&O[(size_t)(b*2048 + q0 + l15) * 1024 + h*64 + f*16 + l4*4] = o;
  }
}

extern "C" void kernel_launch(void* const* d_in, const int* in_sizes, int n_in,
                              void* d_out, int out_size, void* d_ws, size_t ws_size,
                              hipStream_t stream) {
  const float* x    = (const float*)d_in[0];
  const int*   mask = (const int*)  d_in[1];
  const float* Wq   = (const float*)d_in[2];
  const float* Wkv  = (const float*)d_in[3];
  const float* Wo   = (const float*)d_in[4];
  float* out = (float*)d_out;

  char* ws = (char*)d_ws;
  short* xb  = (short*)(ws);                 //  8 MB  [4096][1024]
  short* W1T = (short*)(ws + 8388608);       //  6 MB  [3072][1024]
  short* WoT = (short*)(ws + 14680064);      //  2 MB  [1024][1024]
  short* QKV = (short*)(ws + 16777216);      // 24 MB  [4096][3072]
  short* VT  = (short*)(ws + 41943040);      //  8 MB  [32*64][2048]
  short* O   = (short*)(ws + 50331648);      //  8 MB  [4096][1024]

  cvt_f32_bf16<<<4096, 256, 0, stream>>>(x, xb, 4194304 / 4);
  transpose_cvt<<<dim3(32, 32), dim3(32, 8), 0, stream>>>(Wq,  W1T,             1024, 1024);
  transpose_cvt<<<dim3(64, 32), dim3(32, 8), 0, stream>>>(Wkv, W1T + 1024*1024, 1024, 2048);
  transpose_cvt<<<dim3(32, 32), dim3(32, 8), 0, stream>>>(Wo,  WoT,             1024, 1024);
  gemm_bt<0><<<dim3(24, 32), 256, 0, stream>>>(xb, W1T, QKV, 4096, 3072, 1024);
  transpose_v<<<dim3(64, 32), dim3(32, 8), 0, stream>>>(QKV, VT);
  attn_kernel<<<dim3(32, 32), 256, 0, stream>>>(QKV, VT, mask, O);
  gemm_bt<1><<<dim3(8, 32), 256, 0, stream>>>(O, WoT, out, 4096, 1024, 1024);
}

// Round 6
// 230.970 us; speedup vs baseline: 1.6628x; 1.1621x over previous
//
#include <hip/hip_runtime.h>
#include <stdint.h>

typedef __attribute__((ext_vector_type(4))) float f32x4;
typedef __attribute__((ext_vector_type(8))) short s16x8;
typedef __attribute__((ext_vector_type(4))) short s16x4;

// Problem constants: B=2, N=2048, DIM=1024, H=16, DH=64, DI=1024, M = B*N = 4096

__device__ __forceinline__ short f2bf(float f) {
  union { float f; unsigned u; } v; v.f = f;
  unsigned r = (v.u + 0x7fff + ((v.u >> 16) & 1)) >> 16;  // RNE
  return (short)r;
}

__device__ __forceinline__ unsigned cvtpk(float lo, float hi) {
  unsigned r;
  asm("v_cvt_pk_bf16_f32 %0, %1, %2" : "=v"(r) : "v"(lo), "v"(hi));
  return r;
}

__device__ __forceinline__ void gload16(const void* g, void* l) {
  __builtin_amdgcn_global_load_lds(
      (const __attribute__((address_space(1))) unsigned int*)g,
      (__attribute__((address_space(3))) unsigned int*)l, 16, 0, 0);
}

// ---------------- fp32 -> bf16 convert (vectorized) ----------------
__global__ __launch_bounds__(256) void cvt_f32_bf16(const float* __restrict__ in,
                                                    short* __restrict__ out, int n4) {
  int i = blockIdx.x * 256 + threadIdx.x;
  if (i >= n4) return;
  float4 f = ((const float4*)in)[i];
  s16x4 o; o.x = f2bf(f.x); o.y = f2bf(f.y); o.z = f2bf(f.z); o.w = f2bf(f.w);
  ((s16x4*)out)[i] = o;
}

// ---------------- transpose+convert+scale: in[K][N] f32 -> out[N][K] bf16 ----------------
__global__ void transpose_cvt(const float* __restrict__ in, short* __restrict__ out,
                              int K, int N, float scale) {
  __shared__ float t[32][33];
  int nt = blockIdx.x * 32, kt = blockIdx.y * 32;
  int tx = threadIdx.x, ty = threadIdx.y;  // 32 x 8
  #pragma unroll
  for (int i = 0; i < 4; i++) t[ty + 8*i][tx] = in[(size_t)(kt + ty + 8*i) * N + nt + tx];
  __syncthreads();
  #pragma unroll
  for (int i = 0; i < 4; i++)
    out[(size_t)(nt + ty + 8*i) * K + kt + tx] = f2bf(t[tx][ty + 8*i] * scale);
}

// ---------------- QKV GEMM: QKV[4096][c] = xb * W1T^T; V region written transposed ----------------
// cols 0..2047 -> QKV[row][col]; cols 2048..3071 -> VT[(b*16+h)*64+d][n] (packed 8B stores)
__global__ __launch_bounds__(256) void gemm_qkv(const short* __restrict__ A,
                                                const short* __restrict__ Bt,
                                                short* __restrict__ QKV,
                                                short* __restrict__ VT) {
  const int N = 3072, K = 1024;
  __shared__ short As[128][32];
  __shared__ short Bs[128][32];
  const int tid = threadIdx.x;
  const int wave = tid >> 6, lane = tid & 63;
  const int l15 = lane & 15, l4 = lane >> 4;
  const int bm = blockIdx.y * 128, bn = blockIdx.x * 128;
  const int wr = (wave >> 1) * 64, wc = (wave & 1) * 64;
  const int r = tid >> 2, c8 = (tid & 3) * 8;
  const short* aS0 = &A [(size_t)(bm + r)      * K + c8];
  const short* aS1 = &A [(size_t)(bm + 64 + r) * K + c8];
  const short* bS0 = &Bt[(size_t)(bn + r)      * K + c8];
  const short* bS1 = &Bt[(size_t)(bn + 64 + r) * K + c8];
  char* aD0 = (char*)As + tid*16; char* aD1 = (char*)As + 4096 + tid*16;
  char* bD0 = (char*)Bs + tid*16; char* bD1 = (char*)Bs + 4096 + tid*16;
  f32x4 acc[4][4] = {};
  for (int k0 = 0; k0 < K; k0 += 32) {
    gload16(aS0 + k0, aD0);
    gload16(aS1 + k0, aD1);
    gload16(bS0 + k0, bD0);
    gload16(bS1 + k0, bD1);
    __syncthreads();
    s16x8 af[4], bf[4];
    #pragma unroll
    for (int m = 0; m < 4; m++) af[m] = *(const s16x8*)&As[wr + m*16 + l15][l4*8];
    #pragma unroll
    for (int n = 0; n < 4; n++) bf[n] = *(const s16x8*)&Bs[wc + n*16 + l15][l4*8];
    #pragma unroll
    for (int m = 0; m < 4; m++)
      #pragma unroll
      for (int n = 0; n < 4; n++)
        acc[m][n] = __builtin_amdgcn_mfma_f32_16x16x32_bf16(af[m], bf[n], acc[m][n], 0, 0, 0);
    __syncthreads();
  }
  #pragma unroll
  for (int m = 0; m < 4; m++)
    #pragma unroll
    for (int n = 0; n < 4; n++) {
      const int row0 = bm + wr + m*16 + l4*4;   // +j for j in 0..3
      const int col  = bn + wc + n*16 + l15;
      if (col < 2048) {
        #pragma unroll
        for (int j = 0; j < 4; j++)
          QKV[(size_t)(row0 + j) * 3072 + col] = f2bf(acc[m][n][j]);
      } else {
        // V: write transposed, 4 consecutive n's packed (8B)
        const int c2 = col - 2048;
        const size_t vtIdx = ((size_t)((row0 >> 11) * 1024 + c2)) * 2048 + (row0 & 2047);
        uint2 pk2;
        pk2.x = cvtpk(acc[m][n][0], acc[m][n][1]);
        pk2.y = cvtpk(acc[m][n][2], acc[m][n][3]);
        *(uint2*)&VT[vtIdx] = pk2;
      }
    }
}

// ---------------- out-proj GEMM: out[4096][1024] f32 = O * WoT^T, BM=64 tiles ----------------
__global__ __launch_bounds__(256) void gemm_out(const short* __restrict__ A,
                                                const short* __restrict__ Bt,
                                                float* __restrict__ C) {
  const int N = 1024, K = 1024;
  __shared__ short As[64][32];
  __shared__ short Bs[128][32];
  const int tid = threadIdx.x;
  const int wave = tid >> 6, lane = tid & 63;
  const int l15 = lane & 15, l4 = lane >> 4;
  const int bm = blockIdx.y * 64, bn = blockIdx.x * 128;
  const int wr = (wave >> 1) * 32, wc = (wave & 1) * 64;
  const int r = tid >> 2, c8 = (tid & 3) * 8;
  const short* aS0 = &A [(size_t)(bm + r)      * K + c8];
  const short* bS0 = &Bt[(size_t)(bn + r)      * K + c8];
  const short* bS1 = &Bt[(size_t)(bn + 64 + r) * K + c8];
  char* aD0 = (char*)As + tid*16;
  char* bD0 = (char*)Bs + tid*16; char* bD1 = (char*)Bs + 4096 + tid*16;
  f32x4 acc[2][4] = {};
  for (int k0 = 0; k0 < K; k0 += 32) {
    gload16(aS0 + k0, aD0);
    gload16(bS0 + k0, bD0);
    gload16(bS1 + k0, bD1);
    __syncthreads();
    s16x8 af[2], bf[4];
    #pragma unroll
    for (int m = 0; m < 2; m++) af[m] = *(const s16x8*)&As[wr + m*16 + l15][l4*8];
    #pragma unroll
    for (int n = 0; n < 4; n++) bf[n] = *(const s16x8*)&Bs[wc + n*16 + l15][l4*8];
    #pragma unroll
    for (int m = 0; m < 2; m++)
      #pragma unroll
      for (int n = 0; n < 4; n++)
        acc[m][n] = __builtin_amdgcn_mfma_f32_16x16x32_bf16(af[m], bf[n], acc[m][n], 0, 0, 0);
    __syncthreads();
  }
  #pragma unroll
  for (int m = 0; m < 2; m++)
    #pragma unroll
    for (int n = 0; n < 4; n++)
      #pragma unroll
      for (int j = 0; j < 4; j++) {
        int row = bm + wr + m*16 + l4*4 + j;
        int col = bn + wc + n*16 + l15;
        C[(size_t)row * N + col] = acc[m][n][j];
      }
}

// ---------------- fused masked flash attention ----------------
// KVBLK=64, K/V double-buffered LDS (XOR-swizzled), one __syncthreads per tile.
// Softmax: bias as MFMA C-operand; scale pre-folded into Wq (exp2 domain);
// defer-max via psum<=512 check (init m=12); v_exp_f32 + cvt_pk packing.
__global__ __launch_bounds__(256) void attn_kernel(const short* __restrict__ QKV,
                                                   const short* __restrict__ VT,
                                                   const int* __restrict__ mask,
                                                   short* __restrict__ O) {
  __shared__ float biasLds[2048];
  __shared__ short Ks[2][64*64];    // swizzled [key][d]
  __shared__ short Vs[2][64*64];    // swizzled [d][key]
  __shared__ short Pl[4][16*64];    // per-wave swizzled [q][key]

  // XCD swizzle: 1024 blocks, 8 XCDs, 128 contiguous wgs each -> 4 heads/XCD
  const int orig = blockIdx.y * 32 + blockIdx.x;
  const int wg = (orig & 7) * 128 + (orig >> 3);
  const int qt = wg & 31;      // 0..31
  const int bh = wg >> 5;      // 0..31
  const int b = bh >> 4, h = bh & 15;
  const int tid = threadIdx.x;
  const int wave = tid >> 6, lane = tid & 63;
  const int l15 = lane & 15, l4 = lane >> 4;

  const int q0 = qt * 64 + wave * 16;
  s16x8 qb0 = *(const s16x8*)&QKV[(size_t)(b*2048 + q0 + l15) * 3072 + h*64 + l4*8];
  s16x8 qb1 = *(const s16x8*)&QKV[(size_t)(b*2048 + q0 + l15) * 3072 + h*64 + 32 + l4*8];

  for (int j = tid; j < 2048; j += 256)
    biasLds[j] = mask[b*2048 + j] ? 0.0f : -1e38f;

  const int r0 = tid >> 3, c0 = tid & 7;
  const int cs = (c0 ^ (r0 & 7)) * 8;   // pre-swizzled source (shorts)
  const short* Kg = QKV + (size_t)(b*2048)*3072 + 1024 + h*64;
  const short* Vg = VT + (size_t)(bh*64)*2048;
  const short* kS0 = Kg + (size_t)r0*3072 + cs;
  const short* kS1 = Kg + (size_t)(r0+32)*3072 + cs;
  const short* vS0 = Vg + (size_t)r0*2048 + cs;
  const short* vS1 = Vg + (size_t)(r0+32)*2048 + cs;

  gload16(kS0, (char*)Ks[0] + tid*16);
  gload16(kS1, (char*)Ks[0] + 4096 + tid*16);
  gload16(vS0, (char*)Vs[0] + tid*16);
  gload16(vS1, (char*)Vs[0] + 4096 + tid*16);
  __syncthreads();   // bias + tile 0 ready

  f32x4 oacc[4] = {};
  float mrun = 12.0f, lsum = 0.0f;   // exp2-domain; P bounded by 512 via psum check
  const int swz = (l15 & 7) << 4;
  char* PlB = (char*)&Pl[wave][0];
  const int rowB = l15 * 128;

  #pragma unroll 2
  for (int kt = 0; kt < 32; kt++) {
    const int cur = kt & 1;
    if (kt + 1 < 32) {
      gload16(kS0 + (size_t)(kt+1)*196608, (char*)Ks[cur^1] + tid*16);
      gload16(kS1 + (size_t)(kt+1)*196608, (char*)Ks[cur^1] + 4096 + tid*16);
      gload16(vS0 + (kt+1)*64,             (char*)Vs[cur^1] + tid*16);
      gload16(vS1 + (kt+1)*64,             (char*)Vs[cur^1] + 4096 + tid*16);
    }
    const char* KsB = (const char*)Ks[cur];
    const char* VsB = (const char*)Vs[cur];

    // ---- QK^T (swapped): vals = S*scale(log2e) + maskbias, bias as C-operand ----
    float vals[16];
    #pragma unroll
    for (int g = 0; g < 4; g++) {
      f32x4 cb = *(const f32x4*)&biasLds[kt*64 + g*16 + l4*4];
      s16x8 ka0 = *(const s16x8*)(KsB + (g*16 + l15)*128 + ((l4*16) ^ swz));
      s16x8 ka1 = *(const s16x8*)(KsB + (g*16 + l15)*128 + ((64 + l4*16) ^ swz));
      f32x4 s = __builtin_amdgcn_mfma_f32_16x16x32_bf16(ka0, qb0, cb, 0, 0, 0);
      s       = __builtin_amdgcn_mfma_f32_16x16x32_bf16(ka1, qb1, s,  0, 0, 0);
      #pragma unroll
      for (int rr = 0; rr < 4; rr++) vals[g*4 + rr] = s[rr];
    }
    // ---- exp with OLD max (no max-chain on critical path) ----
    float p[16], psum = 0.f;
    #pragma unroll
    for (int i = 0; i < 16; i++) { p[i] = __builtin_amdgcn_exp2f(vals[i] - mrun); psum += p[i]; }
    psum += __shfl_xor(psum, 16);
    psum += __shfl_xor(psum, 32);
    if (!__all(psum <= 512.0f)) {   // rare rescale path (wave-uniform)
      float tm = vals[0];
      #pragma unroll
      for (int i = 1; i < 16; i++) tm = fmaxf(tm, vals[i]);
      tm = fmaxf(tm, __shfl_xor(tm, 16));
      tm = fmaxf(tm, __shfl_xor(tm, 32));
      float mnew = fmaxf(mrun, tm);
      float corr = __builtin_amdgcn_exp2f(mrun - mnew);
      psum = 0.f;
      #pragma unroll
      for (int i = 0; i < 16; i++) { p[i] = __builtin_amdgcn_exp2f(vals[i] - mnew); psum += p[i]; }
      psum += __shfl_xor(psum, 16);
      psum += __shfl_xor(psum, 32);
      #pragma unroll
      for (int f = 0; f < 4; f++)
        #pragma unroll
        for (int j = 0; j < 4; j++) oacc[f][j] *= corr;
      lsum *= corr;
      mrun = mnew;
    }
    lsum += psum;
    #pragma unroll
    for (int g = 0; g < 4; g++) {
      uint2 pk2;
      pk2.x = cvtpk(p[g*4+0], p[g*4+1]);
      pk2.y = cvtpk(p[g*4+2], p[g*4+3]);
      *(uint2*)(PlB + rowB + ((g*32 + l4*8) ^ swz)) = pk2;
    }

    // ---- PV: O^T += V^T * P^T ----
    #pragma unroll
    for (int kh = 0; kh < 2; kh++) {
      s16x8 pb = *(const s16x8*)(PlB + rowB + ((kh*64 + l4*16) ^ swz));
      #pragma unroll
      for (int f = 0; f < 4; f++) {
        s16x8 vf = *(const s16x8*)(VsB + (f*16 + l15)*128 + ((kh*64 + l4*16) ^ swz));
        oacc[f] = __builtin_amdgcn_mfma_f32_16x16x32_bf16(vf, pb, oacc[f], 0, 0, 0);
      }
    }
    __syncthreads();  // all waves done with buf[cur]; prefetch drained
  }

  float inv = 1.0f / lsum;
  #pragma unroll
  for (int f = 0; f < 4; f++) {
    uint2 o;
    o.x = cvtpk(oacc[f][0] * inv, oacc[f][1] * inv);
    o.y = cvtpk(oacc[f][2] * inv, oacc[f][3] * inv);
    *(uint2*)&O[(size_t)(b*2048 + q0 + l15) * 1024 + h*64 + f*16 + l4*4] = o;
  }
}

extern "C" void kernel_launch(void* const* d_in, const int* in_sizes, int n_in,
                              void* d_out, int out_size, void* d_ws, size_t ws_size,
                              hipStream_t stream) {
  const float* x    = (const float*)d_in[0];
  const int*   mask = (const int*)  d_in[1];
  const float* Wq   = (const float*)d_in[2];
  const float* Wkv  = (const float*)d_in[3];
  const float* Wo   = (const float*)d_in[4];
  float* out = (float*)d_out;

  char* ws = (char*)d_ws;
  short* xb  = (short*)(ws);                 //  8 MB  [4096][1024]
  short* W1T = (short*)(ws + 8388608);       //  6 MB  [3072][1024]
  short* WoT = (short*)(ws + 14680064);      //  2 MB  [1024][1024]
  short* QKV = (short*)(ws + 16777216);      // 24 MB  [4096][3072] (V region unused)
  short* VT  = (short*)(ws + 41943040);      //  8 MB  [32*64][2048]
  short* O   = (short*)(ws + 50331648);      //  8 MB  [4096][1024]

  const float qscale = 0.18033688011112042f;  // dh^-0.5 * log2(e)

  cvt_f32_bf16<<<4096, 256, 0, stream>>>(x, xb, 4194304 / 4);
  transpose_cvt<<<dim3(32, 32), dim3(32, 8), 0, stream>>>(Wq,  W1T,             1024, 1024, qscale);
  transpose_cvt<<<dim3(64, 32), dim3(32, 8), 0, stream>>>(Wkv, W1T + 1024*1024, 1024, 2048, 1.0f);
  transpose_cvt<<<dim3(32, 32), dim3(32, 8), 0, stream>>>(Wo,  WoT,             1024, 1024, 1.0f);
  gemm_qkv<<<dim3(24, 32), 256, 0, stream>>>(xb, W1T, QKV, VT);
  attn_kernel<<<dim3(32, 32), 256, 0, stream>>>(QKV, VT, mask, O);
  gemm_out<<<dim3(8, 64), 256, 0, stream>>>(O, WoT, out);
}

// Round 7
// 208.784 us; speedup vs baseline: 1.8395x; 1.1063x over previous
//
#include <hip/hip_runtime.h>
#include <stdint.h>

typedef __attribute__((ext_vector_type(4))) float f32x4;
typedef __attribute__((ext_vector_type(8))) short s16x8;
typedef __attribute__((ext_vector_type(4))) short s16x4;

// Problem constants: B=2, N=2048, DIM=1024, H=16, DH=64, DI=1024, M = B*N = 4096

__device__ __forceinline__ short f2bf(float f) {
  union { float f; unsigned u; } v; v.f = f;
  unsigned r = (v.u + 0x7fff + ((v.u >> 16) & 1)) >> 16;  // RNE
  return (short)r;
}

__device__ __forceinline__ unsigned cvtpk(float lo, float hi) {
  unsigned r;
  asm("v_cvt_pk_bf16_f32 %0, %1, %2" : "=v"(r) : "v"(lo), "v"(hi));
  return r;
}

__device__ __forceinline__ void gload16(const void* g, void* l) {
  __builtin_amdgcn_global_load_lds(
      (const __attribute__((address_space(1))) unsigned int*)g,
      (__attribute__((address_space(3))) unsigned int*)l, 16, 0, 0);
}

// ---------------- fp32 -> bf16 convert (vectorized) ----------------
__global__ __launch_bounds__(256) void cvt_f32_bf16(const float* __restrict__ in,
                                                    short* __restrict__ out, int n4) {
  int i = blockIdx.x * 256 + threadIdx.x;
  if (i >= n4) return;
  float4 f = ((const float4*)in)[i];
  s16x4 o; o.x = f2bf(f.x); o.y = f2bf(f.y); o.z = f2bf(f.z); o.w = f2bf(f.w);
  ((s16x4*)out)[i] = o;
}

// ---------------- fused transpose+convert of all three weights ----------------
// Wq (scaled), Wkv, Wo: in[1024][N] f32 -> out[N][1024] bf16.
__global__ void transpose_cvt3(const float* __restrict__ Wq, const float* __restrict__ Wkv,
                               const float* __restrict__ Wo, short* __restrict__ W1T,
                               short* __restrict__ WoT, float qscale) {
  int bid = blockIdx.x;
  const float* in; short* out; int N; float scale;
  if (bid < 1024)      { in = Wq;  out = W1T;              N = 1024; scale = qscale; }
  else if (bid < 3072) { bid -= 1024; in = Wkv; out = W1T + 1024*1024; N = 2048; scale = 1.f; }
  else                 { bid -= 3072; in = Wo;  out = WoT;             N = 1024; scale = 1.f; }
  const int nb = N >> 5;
  const int nt = (bid % nb) * 32, kt = (bid / nb) * 32;
  __shared__ float t[32][33];
  int tx = threadIdx.x, ty = threadIdx.y;  // 32 x 8
  #pragma unroll
  for (int i = 0; i < 4; i++) t[ty + 8*i][tx] = in[(size_t)(kt + ty + 8*i) * N + nt + tx];
  __syncthreads();
  #pragma unroll
  for (int i = 0; i < 4; i++)
    out[(size_t)(nt + ty + 8*i) * 1024 + kt + tx] = f2bf(t[tx][ty + 8*i] * scale);
}

// ---------------- QKV GEMM (double-buffered): QKV = xb * W1T^T; V written transposed ----------------
__global__ __launch_bounds__(256) void gemm_qkv(const short* __restrict__ A,
                                                const short* __restrict__ Bt,
                                                short* __restrict__ QKV,
                                                short* __restrict__ VT) {
  const int K = 1024;
  __shared__ short As[2][128][32];
  __shared__ short Bs[2][128][32];
  const int tid = threadIdx.x;
  const int wave = tid >> 6, lane = tid & 63;
  const int l15 = lane & 15, l4 = lane >> 4;
  const int bm = blockIdx.y * 128, bn = blockIdx.x * 128;
  const int wr = (wave >> 1) * 64, wc = (wave & 1) * 64;
  const int r = tid >> 2, c8 = (tid & 3) * 8;
  const short* aS0 = &A [(size_t)(bm + r)      * K + c8];
  const short* aS1 = &A [(size_t)(bm + 64 + r) * K + c8];
  const short* bS0 = &Bt[(size_t)(bn + r)      * K + c8];
  const short* bS1 = &Bt[(size_t)(bn + 64 + r) * K + c8];
  f32x4 acc[4][4] = {};
  // prologue: stage K-step 0 into buf 0
  gload16(aS0, (char*)As + tid*16);
  gload16(aS1, (char*)As + 4096 + tid*16);
  gload16(bS0, (char*)Bs + tid*16);
  gload16(bS1, (char*)Bs + 4096 + tid*16);
  __syncthreads();
  #pragma unroll 2
  for (int kk = 0; kk < 32; kk++) {
    const int cur = kk & 1;
    if (kk + 1 < 32) {
      const int k1 = (kk + 1) * 32;
      gload16(aS0 + k1, (char*)As + (cur^1)*8192 + tid*16);
      gload16(aS1 + k1, (char*)As + (cur^1)*8192 + 4096 + tid*16);
      gload16(bS0 + k1, (char*)Bs + (cur^1)*8192 + tid*16);
      gload16(bS1 + k1, (char*)Bs + (cur^1)*8192 + 4096 + tid*16);
    }
    s16x8 af[4], bf[4];
    #pragma unroll
    for (int m = 0; m < 4; m++) af[m] = *(const s16x8*)&As[cur][wr + m*16 + l15][l4*8];
    #pragma unroll
    for (int n = 0; n < 4; n++) bf[n] = *(const s16x8*)&Bs[cur][wc + n*16 + l15][l4*8];
    #pragma unroll
    for (int m = 0; m < 4; m++)
      #pragma unroll
      for (int n = 0; n < 4; n++)
        acc[m][n] = __builtin_amdgcn_mfma_f32_16x16x32_bf16(af[m], bf[n], acc[m][n], 0, 0, 0);
    __syncthreads();   // readers done with buf[cur]; prefetch into buf[cur^1] drained
  }
  #pragma unroll
  for (int m = 0; m < 4; m++)
    #pragma unroll
    for (int n = 0; n < 4; n++) {
      const int row0 = bm + wr + m*16 + l4*4;
      const int col  = bn + wc + n*16 + l15;
      if (col < 2048) {
        #pragma unroll
        for (int j = 0; j < 4; j++)
          QKV[(size_t)(row0 + j) * 3072 + col] = f2bf(acc[m][n][j]);
      } else {
        const int c2 = col - 2048;
        const size_t vtIdx = ((size_t)((row0 >> 11) * 1024 + c2)) * 2048 + (row0 & 2047);
        uint2 pk2;
        pk2.x = cvtpk(acc[m][n][0], acc[m][n][1]);
        pk2.y = cvtpk(acc[m][n][2], acc[m][n][3]);
        *(uint2*)&VT[vtIdx] = pk2;
      }
    }
}

// ---------------- out-proj GEMM (double-buffered): out f32 = O * WoT^T ----------------
__global__ __launch_bounds__(256) void gemm_out(const short* __restrict__ A,
                                                const short* __restrict__ Bt,
                                                float* __restrict__ C) {
  const int N = 1024, K = 1024;
  __shared__ short As[2][64][32];
  __shared__ short Bs[2][128][32];
  const int tid = threadIdx.x;
  const int wave = tid >> 6, lane = tid & 63;
  const int l15 = lane & 15, l4 = lane >> 4;
  const int bm = blockIdx.y * 64, bn = blockIdx.x * 128;
  const int wr = (wave >> 1) * 32, wc = (wave & 1) * 64;
  const int r = tid >> 2, c8 = (tid & 3) * 8;
  const short* aS0 = &A [(size_t)(bm + r)      * K + c8];
  const short* bS0 = &Bt[(size_t)(bn + r)      * K + c8];
  const short* bS1 = &Bt[(size_t)(bn + 64 + r) * K + c8];
  f32x4 acc[2][4] = {};
  if (r < 64) gload16(aS0, (char*)As + tid*16);   // A tile is 64 rows: threads 0..255 map r=0..63, 4 chunks
  gload16(bS0, (char*)Bs + tid*16);
  gload16(bS1, (char*)Bs + 4096 + tid*16);
  __syncthreads();
  #pragma unroll 2
  for (int kk = 0; kk < 32; kk++) {
    const int cur = kk & 1;
    if (kk + 1 < 32) {
      const int k1 = (kk + 1) * 32;
      gload16(aS0 + k1, (char*)As + (cur^1)*4096 + tid*16);
      gload16(bS0 + k1, (char*)Bs + (cur^1)*8192 + tid*16);
      gload16(bS1 + k1, (char*)Bs + (cur^1)*8192 + 4096 + tid*16);
    }
    s16x8 af[2], bf[4];
    #pragma unroll
    for (int m = 0; m < 2; m++) af[m] = *(const s16x8*)&As[cur][wr + m*16 + l15][l4*8];
    #pragma unroll
    for (int n = 0; n < 4; n++) bf[n] = *(const s16x8*)&Bs[cur][wc + n*16 + l15][l4*8];
    #pragma unroll
    for (int m = 0; m < 2; m++)
      #pragma unroll
      for (int n = 0; n < 4; n++)
        acc[m][n] = __builtin_amdgcn_mfma_f32_16x16x32_bf16(af[m], bf[n], acc[m][n], 0, 0, 0);
    __syncthreads();
  }
  #pragma unroll
  for (int m = 0; m < 2; m++)
    #pragma unroll
    for (int n = 0; n < 4; n++)
      #pragma unroll
      for (int j = 0; j < 4; j++) {
        int row = bm + wr + m*16 + l4*4 + j;
        int col = bn + wc + n*16 + l15;
        C[(size_t)row * N + col] = acc[m][n][j];
      }
}

// ---------------- fused masked flash attention ----------------
// QBLK=128 (4 waves x 32 q-rows), KVBLK=64, K/V double-buffered LDS
// (XOR-swizzled), one __syncthreads per tile. K-fragments shared across the
// wave's two 16-q groups. 512 blocks = exactly 2/CU at 56KB LDS.
__global__ __launch_bounds__(256) void attn_kernel(const short* __restrict__ QKV,
                                                   const short* __restrict__ VT,
                                                   const int* __restrict__ mask,
                                                   short* __restrict__ O) {
  __shared__ float biasLds[2048];
  __shared__ short Ks[2][64*64];    // swizzled [key][d]
  __shared__ short Vs[2][64*64];    // swizzled [d][key]
  __shared__ short Pl[4][32*64];    // per-wave swizzled [q][key]

  // XCD swizzle: 512 blocks, 8 XCDs, 64 contiguous wgs each -> 4 heads/XCD
  const int orig = blockIdx.y * 16 + blockIdx.x;
  const int wg = (orig & 7) * 64 + (orig >> 3);
  const int qt = wg & 15;      // 0..15 (q tile of 128 rows)
  const int bh = wg >> 4;      // 0..31
  const int b = bh >> 4, h = bh & 15;
  const int tid = threadIdx.x;
  const int wave = tid >> 6, lane = tid & 63;
  const int l15 = lane & 15, l4 = lane >> 4;

  const int q0 = qt * 128 + wave * 32;
  s16x8 qb[2][2];
  #pragma unroll
  for (int qg = 0; qg < 2; qg++)
    #pragma unroll
    for (int s = 0; s < 2; s++)
      qb[qg][s] = *(const s16x8*)&QKV[(size_t)(b*2048 + q0 + qg*16 + l15) * 3072 + h*64 + s*32 + l4*8];

  for (int j = tid; j < 2048; j += 256)
    biasLds[j] = mask[b*2048 + j] ? 0.0f : -1e38f;

  const int r0 = tid >> 3, c0 = tid & 7;
  const int cs = (c0 ^ (r0 & 7)) * 8;   // pre-swizzled source (shorts)
  const short* Kg = QKV + (size_t)(b*2048)*3072 + 1024 + h*64;
  const short* Vg = VT + (size_t)(bh*64)*2048;
  const short* kS0 = Kg + (size_t)r0*3072 + cs;
  const short* kS1 = Kg + (size_t)(r0+32)*3072 + cs;
  const short* vS0 = Vg + (size_t)r0*2048 + cs;
  const short* vS1 = Vg + (size_t)(r0+32)*2048 + cs;

  gload16(kS0, (char*)Ks[0] + tid*16);
  gload16(kS1, (char*)Ks[0] + 4096 + tid*16);
  gload16(vS0, (char*)Vs[0] + tid*16);
  gload16(vS1, (char*)Vs[0] + 4096 + tid*16);
  __syncthreads();   // bias + tile 0 ready

  f32x4 oacc[2][4] = {};
  float mrun[2] = {12.0f, 12.0f}, lsum[2] = {0.0f, 0.0f};
  const int swz = (l15 & 7) << 4;
  char* PlB = (char*)&Pl[wave][0];

  #pragma unroll 2
  for (int kt = 0; kt < 32; kt++) {
    const int cur = kt & 1;
    if (kt + 1 < 32) {
      gload16(kS0 + (size_t)(kt+1)*196608, (char*)Ks[cur^1] + tid*16);
      gload16(kS1 + (size_t)(kt+1)*196608, (char*)Ks[cur^1] + 4096 + tid*16);
      gload16(vS0 + (kt+1)*64,             (char*)Vs[cur^1] + tid*16);
      gload16(vS1 + (kt+1)*64,             (char*)Vs[cur^1] + 4096 + tid*16);
    }
    const char* KsB = (const char*)Ks[cur];
    const char* VsB = (const char*)Vs[cur];

    // ---- QK^T for both q-groups, K fragments loaded once ----
    s16x8 ka[4][2];
    #pragma unroll
    for (int g = 0; g < 4; g++) {
      ka[g][0] = *(const s16x8*)(KsB + (g*16 + l15)*128 + ((l4*16) ^ swz));
      ka[g][1] = *(const s16x8*)(KsB + (g*16 + l15)*128 + ((64 + l4*16) ^ swz));
    }
    f32x4 sv[2][4];
    #pragma unroll
    for (int g = 0; g < 4; g++) {
      f32x4 cb = *(const f32x4*)&biasLds[kt*64 + g*16 + l4*4];
      #pragma unroll
      for (int qg = 0; qg < 2; qg++) {
        f32x4 s = __builtin_amdgcn_mfma_f32_16x16x32_bf16(ka[g][0], qb[qg][0], cb, 0, 0, 0);
        sv[qg][g] = __builtin_amdgcn_mfma_f32_16x16x32_bf16(ka[g][1], qb[qg][1], s, 0, 0, 0);
      }
    }

    // ---- per q-group: softmax (defer-max), P write, PV ----
    #pragma unroll
    for (int qg = 0; qg < 2; qg++) {
      const int rowB = (qg*16 + l15) * 128;
      float p[16], psum = 0.f;
      #pragma unroll
      for (int g = 0; g < 4; g++)
        #pragma unroll
        for (int rr = 0; rr < 4; rr++) {
          p[g*4+rr] = __builtin_amdgcn_exp2f(sv[qg][g][rr] - mrun[qg]);
          psum += p[g*4+rr];
        }
      psum += __shfl_xor(psum, 16);
      psum += __shfl_xor(psum, 32);
      if (!__all(psum <= 512.0f)) {   // rare rescale path (wave-uniform)
        float tm = sv[qg][0][0];
        #pragma unroll
        for (int g = 0; g < 4; g++)
          #pragma unroll
          for (int rr = 0; rr < 4; rr++) tm = fmaxf(tm, sv[qg][g][rr]);
        tm = fmaxf(tm, __shfl_xor(tm, 16));
        tm = fmaxf(tm, __shfl_xor(tm, 32));
        float mnew = fmaxf(mrun[qg], tm);
        float corr = __builtin_amdgcn_exp2f(mrun[qg] - mnew);
        psum = 0.f;
        #pragma unroll
        for (int g = 0; g < 4; g++)
          #pragma unroll
          for (int rr = 0; rr < 4; rr++) {
            p[g*4+rr] = __builtin_amdgcn_exp2f(sv[qg][g][rr] - mnew);
            psum += p[g*4+rr];
          }
        psum += __shfl_xor(psum, 16);
        psum += __shfl_xor(psum, 32);
        #pragma unroll
        for (int f = 0; f < 4; f++)
          #pragma unroll
          for (int j = 0; j < 4; j++) oacc[qg][f][j] *= corr;
        lsum[qg] *= corr;
        mrun[qg] = mnew;
      }
      lsum[qg] += psum;
      #pragma unroll
      for (int g = 0; g < 4; g++) {
        uint2 pk2;
        pk2.x = cvtpk(p[g*4+0], p[g*4+1]);
        pk2.y = cvtpk(p[g*4+2], p[g*4+3]);
        *(uint2*)(PlB + rowB + ((g*32 + l4*8) ^ swz)) = pk2;
      }
      // PV: O^T += V^T * P^T
      #pragma unroll
      for (int kh = 0; kh < 2; kh++) {
        s16x8 pb = *(const s16x8*)(PlB + rowB + ((kh*64 + l4*16) ^ swz));
        #pragma unroll
        for (int f = 0; f < 4; f++) {
          s16x8 vf = *(const s16x8*)(VsB + (f*16 + l15)*128 + ((kh*64 + l4*16) ^ swz));
          oacc[qg][f] = __builtin_amdgcn_mfma_f32_16x16x32_bf16(vf, pb, oacc[qg][f], 0, 0, 0);
        }
      }
    }
    __syncthreads();  // all waves done with buf[cur]; prefetch drained
  }

  #pragma unroll
  for (int qg = 0; qg < 2; qg++) {
    float inv = 1.0f / lsum[qg];
    #pragma unroll
    for (int f = 0; f < 4; f++) {
      uint2 o;
      o.x = cvtpk(oacc[qg][f][0] * inv, oacc[qg][f][1] * inv);
      o.y = cvtpk(oacc[qg][f][2] * inv, oacc[qg][f][3] * inv);
      *(uint2*)&O[(size_t)(b*2048 + q0 + qg*16 + l15) * 1024 + h*64 + f*16 + l4*4] = o;
    }
  }
}

extern "C" void kernel_launch(void* const* d_in, const int* in_sizes, int n_in,
                              void* d_out, int out_size, void* d_ws, size_t ws_size,
                              hipStream_t stream) {
  const float* x    = (const float*)d_in[0];
  const int*   mask = (const int*)  d_in[1];
  const float* Wq   = (const float*)d_in[2];
  const float* Wkv  = (const float*)d_in[3];
  const float* Wo   = (const float*)d_in[4];
  float* out = (float*)d_out;

  char* ws = (char*)d_ws;
  short* xb  = (short*)(ws);                 //  8 MB  [4096][1024]
  short* W1T = (short*)(ws + 8388608);       //  6 MB  [3072][1024]
  short* WoT = (short*)(ws + 14680064);      //  2 MB  [1024][1024]
  short* QKV = (short*)(ws + 16777216);      // 24 MB  [4096][3072] (V region unused)
  short* VT  = (short*)(ws + 41943040);      //  8 MB  [32*64][2048]
  short* O   = (short*)(ws + 50331648);      //  8 MB  [4096][1024]

  const float qscale = 0.18033688011112042f;  // dh^-0.5 * log2(e)

  cvt_f32_bf16<<<4096, 256, 0, stream>>>(x, xb, 4194304 / 4);
  transpose_cvt3<<<4096, dim3(32, 8), 0, stream>>>(Wq, Wkv, Wo, W1T, WoT, qscale);
  gemm_qkv<<<dim3(24, 32), 256, 0, stream>>>(xb, W1T, QKV, VT);
  attn_kernel<<<dim3(16, 32), 256, 0, stream>>>(QKV, VT, mask, O);
  gemm_out<<<dim3(8, 64), 256, 0, stream>>>(O, WoT, out);
}